// Round 1
// baseline (350.417 us; speedup 1.0000x reference)
//
#include <hip/hip_runtime.h>
#include <math.h>

constexpr int B = 2, H = 320, W = 512, D = 64;
constexpr int HW = H * W;
constexpr int R = 10;          // BLOCK // 2
constexpr int SEG = 32;        // rows per vsum thread
constexpr int NSEG = H / SEG;  // 10
constexpr float EPS = 1e-12f;

// Normalize channels: for each tensor t (0=x,1=gt), batch b, pixel hw:
// split 6 channels into left(0..2)/right(3..5), divide by per-pixel L2 norm.
__global__ void k_norm(const float* __restrict__ x, const float* __restrict__ gt,
                       float* __restrict__ nrm) {
    int idx = blockIdx.x * blockDim.x + threadIdx.x;
    int total = 2 * B * HW;
    if (idx >= total) return;
    int t = idx / (B * HW);
    int rem = idx - t * (B * HW);
    int b = rem / HW;
    int hw = rem - b * HW;
    const float* p = (t == 0 ? x : gt) + (size_t)b * 6 * HW + hw;
    float v0 = p[0],      v1 = p[HW],     v2 = p[2 * HW];
    float v3 = p[3 * HW], v4 = p[4 * HW], v5 = p[5 * HW];
    float n1 = fmaxf(sqrtf(v0 * v0 + v1 * v1 + v2 * v2), EPS);
    float n2 = fmaxf(sqrtf(v3 * v3 + v4 * v4 + v5 * v5), EPS);
    float* q = nrm + (size_t)(t * B + b) * 6 * HW + hw;
    q[0] = v0 / n1;      q[HW] = v1 / n1;     q[2 * HW] = v2 / n1;
    q[3 * HW] = v3 / n2; q[4 * HW] = v4 / n2; q[5 * HW] = v5 / n2;
}

// Fused SAD-diff + vertical 21-row box sum (rolling window).
// grid: B*D*NSEG blocks, blockDim = W. Each thread owns column w of a
// 32-row segment of plane (b,d) and slides the 21-row window.
__global__ void k_vsum(const float* __restrict__ nrm, float* __restrict__ vsum, int t) {
    int blk = blockIdx.x;
    int seg = blk % NSEG;
    int rest = blk / NSEG;
    int d = rest % D;
    int b = rest / D;
    int w = threadIdx.x;  // 0..W-1
    const float* Ln = nrm + (size_t)(t * B + b) * 6 * HW;
    const float* Rn = Ln + 3 * HW;
    const bool val = (w >= d);
    const int wr = val ? (w - d) : 0;
    int h0 = seg * SEG;

    auto diff = [&](int h) -> float {
        const float* lp = Ln + h * W + w;
        float l0 = lp[0], l1 = lp[HW], l2 = lp[2 * HW];
        float r0 = 0.f, r1 = 0.f, r2 = 0.f;
        if (val) {
            const float* rp = Rn + h * W + wr;
            r0 = rp[0]; r1 = rp[HW]; r2 = rp[2 * HW];
        }
        return fabsf(l0 - r0) + fabsf(l1 - r1) + fabsf(l2 - r2);
    };

    // initial window for output row h0: rows [h0-R, h0+R] clipped to [0,H)
    float s = 0.f;
    int lo = h0 - R; if (lo < 0) lo = 0;
    int hi = h0 + R; if (hi > H - 1) hi = H - 1;
    for (int hh = lo; hh <= hi; ++hh) s += diff(hh);

    float* vp = vsum + ((size_t)(b * D + d) * H) * W + w;
    for (int i = 0; i < SEG; ++i) {
        int h = h0 + i;
        vp[(size_t)h * W] = s;
        int ha = h + R + 1;
        int hs = h - R;
        if (ha < H) s += diff(ha);
        if (hs >= 0) s -= diff(hs);
    }
}

// Fused horizontal 21-col box sum + argmin over d.
// grid: B*H blocks, blockDim = W. LDS-stage one vsum row per d.
__global__ void k_harg(const float* __restrict__ vsum, float* __restrict__ disp) {
    int b = blockIdx.x / H;
    int h = blockIdx.x % H;
    int w = threadIdx.x;
    __shared__ float row[W];
    float best = 3.4e38f;
    int bestd = 0;
    for (int d = 0; d < D; ++d) {
        row[w] = vsum[((size_t)(b * D + d) * H + h) * W + w];
        __syncthreads();
        float s = 0.f;
#pragma unroll
        for (int k = -R; k <= R; ++k) {
            int ww = w + k;
            if (ww >= 0 && ww < W) s += row[ww];
        }
        if (s < best) { best = s; bestd = d; }  // strict <: first min wins (jnp.argmin)
        __syncthreads();
    }
    disp[(size_t)(b * H + h) * W + w] = (float)bestd;
}

// Deterministic two-stage mean-abs-diff reduction (no atomics, no memset).
__global__ void k_red1(const float* __restrict__ a, const float* __restrict__ b2,
                       float* __restrict__ part, int n) {
    __shared__ float sm[256];
    int tid = threadIdx.x;
    float s = 0.f;
    for (int i = blockIdx.x * 256 + tid; i < n; i += gridDim.x * 256)
        s += fabsf(a[i] - b2[i]);
    sm[tid] = s;
    __syncthreads();
    for (int off = 128; off; off >>= 1) {
        if (tid < off) sm[tid] += sm[tid + off];
        __syncthreads();
    }
    if (!tid) part[blockIdx.x] = sm[0];
}

__global__ void k_red2(const float* __restrict__ part, float* __restrict__ out,
                       int nb, float inv) {
    __shared__ float sm[256];
    int tid = threadIdx.x;
    float s = 0.f;
    for (int i = tid; i < nb; i += 256) s += part[i];
    sm[tid] = s;
    __syncthreads();
    for (int off = 128; off; off >>= 1) {
        if (tid < off) sm[tid] += sm[tid + off];
        __syncthreads();
    }
    if (!tid) out[0] = sm[0] * inv;
}

extern "C" void kernel_launch(void* const* d_in, const int* in_sizes, int n_in,
                              void* d_out, int out_size, void* d_ws, size_t ws_size,
                              hipStream_t stream) {
    const float* x  = (const float*)d_in[0];
    const float* gt = (const float*)d_in[1];

    float* nrm  = (float*)d_ws;                       // 2*B*6*HW floats (15.7 MB)
    float* vsum = nrm  + (size_t)2 * B * 6 * HW;      // B*D*HW floats   (83.9 MB)
    float* disp = vsum + (size_t)B * D * HW;          // 2*B*HW floats   (2.6 MB)
    float* part = disp + (size_t)2 * B * HW;          // 640 floats

    k_norm<<<(2 * B * HW + 255) / 256, 256, 0, stream>>>(x, gt, nrm);

    for (int t = 0; t < 2; ++t) {
        k_vsum<<<B * D * NSEG, W, 0, stream>>>(nrm, vsum, t);
        k_harg<<<B * H, W, 0, stream>>>(vsum, disp + (size_t)t * B * HW);
    }

    constexpr int NB = 640;
    k_red1<<<NB, 256, 0, stream>>>(disp, disp + (size_t)B * HW, part, B * HW);
    k_red2<<<1, 256, 0, stream>>>(part, (float*)d_out, NB, 1.f / (float)(B * HW));
}

// Round 2
// 241.536 us; speedup vs baseline: 1.4508x; 1.4508x over previous
//
#include <hip/hip_runtime.h>
#include <math.h>

constexpr int B = 2, H = 320, W = 512, D = 64;
constexpr int HW = H * W;
constexpr int R = 10;            // BLOCK // 2
constexpr int SEG = 80;          // rows per cost block
constexpr int NSEG = H / SEG;    // 4
constexpr float EPS = 1e-12f;
constexpr int PADW = W + 2 * R;  // 532

// Normalize + pack into float4 planes: nrm4[((t*B+b)*2+side)*HW + hw] = (c0,c1,c2,0)
__global__ void k_norm(const float* __restrict__ x, const float* __restrict__ gt,
                       float4* __restrict__ nrm4) {
    int idx = blockIdx.x * blockDim.x + threadIdx.x;
    if (idx >= 2 * B * HW) return;
    int t = idx / (B * HW);
    int rem = idx - t * (B * HW);
    int b = rem / HW;
    int hw = rem - b * HW;
    const float* p = (t == 0 ? x : gt) + (size_t)b * 6 * HW + hw;
    float v0 = p[0],      v1 = p[HW],     v2 = p[2 * HW];
    float v3 = p[3 * HW], v4 = p[4 * HW], v5 = p[5 * HW];
    float n1 = fmaxf(sqrtf(v0 * v0 + v1 * v1 + v2 * v2), EPS);
    float n2 = fmaxf(sqrtf(v3 * v3 + v4 * v4 + v5 * v5), EPS);
    float4* q = nrm4 + (size_t)(t * B + b) * 2 * HW + hw;
    q[0]  = make_float4(v0 / n1, v1 / n1, v2 / n1, 0.f);
    q[HW] = make_float4(v3 / n2, v4 / n2, v5 / n2, 0.f);
}

// Fused SAD-diff + vertical 21-box (register ring) + horizontal 21-box (LDS row).
// grid: NSEG*B*D blocks of W threads. blk&7 -> (b,seg) so all d-planes sharing
// image rows land on the same XCD (round-robin dispatch): reads hit XCD-L2.
__global__ void k_cost(const float4* __restrict__ nrm4, float* __restrict__ cost, int t) {
    int blk = blockIdx.x;
    int combo = blk & (2 * NSEG - 1);  // 8 combos = B*NSEG
    int d = blk >> 3;
    int b = combo >> 2;
    int seg = combo & (NSEG - 1);
    int w = threadIdx.x;  // 0..W-1
    const float4* L4 = nrm4 + (size_t)(t * B + b) * 2 * HW;
    const float4* R4 = L4 + HW;
    const bool val = (w >= d);
    const int wr = val ? (w - d) : 0;
    const int h0 = seg * SEG;

    __shared__ float srow[2][PADW];
    if (w < R) {  // zero pads once; first __syncthreads orders them before reads
        srow[0][w] = 0.f; srow[1][w] = 0.f;
        srow[0][W + R + w] = 0.f; srow[1][W + R + w] = 0.f;
    }

    auto diff = [&](int h) -> float {
        float4 l = L4[(size_t)h * W + w];
        if (val) {
            float4 r = R4[(size_t)h * W + wr];
            return fabsf(l.x - r.x) + fabsf(l.y - r.y) + fabsf(l.z - r.z);
        }
        return fabsf(l.x) + fabsf(l.y) + fabsf(l.z);  // r_shift == 0 when invalid
    };

    // 21-row window for output row h0, rows outside [0,H) contribute 0
    float ring[2 * R + 1];
    float s = 0.f;
#pragma unroll
    for (int j = 0; j < 2 * R + 1; ++j) {
        int hh = h0 - R + j;
        float v = (hh >= 0 && hh < H) ? diff(hh) : 0.f;
        ring[j] = v;
        s += v;
    }

    float* cp = cost + ((size_t)(b * D + d) * H) * W + w;
    for (int i = 0; i < SEG; ++i) {
        int h = h0 + i;
        float* row = srow[i & 1];
        row[R + w] = s;
        __syncthreads();
        float c = 0.f;
#pragma unroll
        for (int k = 0; k <= 2 * R; ++k) c += row[w + k];
        cp[(size_t)h * W] = c;
        // slide window down one row
        int ha = h + R + 1;
        float nv = (ha < H) ? diff(ha) : 0.f;
        s += nv - ring[0];
#pragma unroll
        for (int j = 0; j < 2 * R; ++j) ring[j] = ring[j + 1];
        ring[2 * R] = nv;
    }
}

// argmin over d; strict < keeps the first (lowest d) min, matching jnp.argmin.
__global__ void k_argmin(const float* __restrict__ cost, float* __restrict__ disp) {
    int idx = blockIdx.x * blockDim.x + threadIdx.x;  // over B*HW
    if (idx >= B * HW) return;
    int b = idx / HW;
    int hw = idx - b * HW;
    const float* cp = cost + (size_t)b * D * HW + hw;
    float best = 3.4e38f;
    int bd = 0;
    for (int d = 0; d < D; ++d) {
        float v = cp[(size_t)d * HW];
        if (v < best) { best = v; bd = d; }
    }
    disp[idx] = (float)bd;
}

// Deterministic two-stage mean-abs-diff reduction.
__global__ void k_red1(const float* __restrict__ a, const float* __restrict__ b2,
                       float* __restrict__ part, int n) {
    __shared__ float sm[256];
    int tid = threadIdx.x;
    float s = 0.f;
    for (int i = blockIdx.x * 256 + tid; i < n; i += gridDim.x * 256)
        s += fabsf(a[i] - b2[i]);
    sm[tid] = s;
    __syncthreads();
    for (int off = 128; off; off >>= 1) {
        if (tid < off) sm[tid] += sm[tid + off];
        __syncthreads();
    }
    if (!tid) part[blockIdx.x] = sm[0];
}

__global__ void k_red2(const float* __restrict__ part, float* __restrict__ out,
                       int nb, float inv) {
    __shared__ float sm[256];
    int tid = threadIdx.x;
    float s = 0.f;
    for (int i = tid; i < nb; i += 256) s += part[i];
    sm[tid] = s;
    __syncthreads();
    for (int off = 128; off; off >>= 1) {
        if (tid < off) sm[tid] += sm[tid + off];
        __syncthreads();
    }
    if (!tid) out[0] = sm[0] * inv;
}

extern "C" void kernel_launch(void* const* d_in, const int* in_sizes, int n_in,
                              void* d_out, int out_size, void* d_ws, size_t ws_size,
                              hipStream_t stream) {
    const float* x  = (const float*)d_in[0];
    const float* gt = (const float*)d_in[1];

    float4* nrm4 = (float4*)d_ws;                          // 2*B*2*HW float4 (21.0 MB)
    float* cost  = (float*)(nrm4 + (size_t)2 * B * 2 * HW); // B*D*HW floats  (83.9 MB)
    float* disp  = cost + (size_t)B * D * HW;               // 2*B*HW floats  (2.6 MB)
    float* part  = disp + (size_t)2 * B * HW;               // 640 floats

    k_norm<<<(2 * B * HW + 255) / 256, 256, 0, stream>>>(x, gt, nrm4);

    for (int t = 0; t < 2; ++t) {
        k_cost<<<B * NSEG * D, W, 0, stream>>>(nrm4, cost, t);
        k_argmin<<<(B * HW + 255) / 256, 256, 0, stream>>>(cost, disp + (size_t)t * B * HW);
    }

    constexpr int NB = 640;
    k_red1<<<NB, 256, 0, stream>>>(disp, disp + (size_t)B * HW, part, B * HW);
    k_red2<<<1, 256, 0, stream>>>(part, (float*)d_out, NB, 1.f / (float)(B * HW));
}

// Round 3
// 203.855 us; speedup vs baseline: 1.7189x; 1.1848x over previous
//
#include <hip/hip_runtime.h>
#include <math.h>

constexpr int B = 2, H = 320, W = 512, D = 64;
constexpr int HW = H * W;
constexpr int R = 10;            // BLOCK // 2
constexpr int SEG = 80;          // output rows per cost block
constexpr int NSEG = H / SEG;    // 4
constexpr int RS = 540;          // vsbuf row stride in words (bank-uniform, 16B-aligned)
constexpr float EPS = 1e-12f;

// Normalize + pack into float4 planes: nrm4[((t*B+b)*2+side)*HW + hw] = (c0,c1,c2,0)
__global__ void k_norm(const float* __restrict__ x, const float* __restrict__ gt,
                       float4* __restrict__ nrm4) {
    int idx = blockIdx.x * blockDim.x + threadIdx.x;
    if (idx >= 2 * B * HW) return;
    int t = idx / (B * HW);
    int rem = idx - t * (B * HW);
    int b = rem / HW;
    int hw = rem - b * HW;
    const float* p = (t == 0 ? x : gt) + (size_t)b * 6 * HW + hw;
    float v0 = p[0],      v1 = p[HW],     v2 = p[2 * HW];
    float v3 = p[3 * HW], v4 = p[4 * HW], v5 = p[5 * HW];
    float n1 = fmaxf(sqrtf(v0 * v0 + v1 * v1 + v2 * v2), EPS);
    float n2 = fmaxf(sqrtf(v3 * v3 + v4 * v4 + v5 * v5), EPS);
    float4* q = nrm4 + (size_t)(t * B + b) * 2 * HW + hw;
    q[0]  = make_float4(v0 / n1, v1 / n1, v2 / n1, 0.f);
    q[HW] = make_float4(v3 / n2, v4 / n2, v5 / n2, 0.f);
}

// Fully-rolling 21x21 box-filtered SAD cost.
// Block = (b, d, 80-row segment), 512 threads.
// Phase 1 (per row): thread t = column w computes one new diff, updates its
//   register vertical sum vs via LDS delay ring (own-column only -> no sync),
//   snapshots vs into vsbuf[j].
// Phase 2 (per 8 rows): thread = (col-run c = t>>3, row j = t&7) reads its
//   28-float window via 7 aligned ds_read_b128 and emits 8 outputs by
//   horizontal rolling. blk&7 -> (b,seg) keeps all 64 d on one XCD (L2 reuse).
__global__ __launch_bounds__(512, 4) void k_cost(const float4* __restrict__ nrm4,
                                                 float* __restrict__ cost, int t) {
    int blk = blockIdx.x;
    int combo = blk & 7;           // B*NSEG = 8 combos
    int d = blk >> 3;
    int b = combo >> 2;
    int seg = combo & 3;
    int w = threadIdx.x;           // phase-1 column
    const float4* L4 = nrm4 + (size_t)(t * B + b) * 2 * HW;
    const float4* R4 = L4 + HW;
    const bool val = (w >= d);
    const int wr = val ? (w - d) : 0;
    const int h0 = seg * SEG;

    __shared__ float ring[21][W];    // diff delay line (per-column, no cross-thread access)
    __shared__ float vsbuf[8][RS];   // vsbuf[j][i] = vs(col = i-10); pads are zero

    {   // zero the halo pads once; never touched again
        int j = w >> 6, k = w & 63;
        if (k < 10) vsbuf[j][k] = 0.f;
        else if (k < 28) vsbuf[j][522 + (k - 10)] = 0.f;
    }

    auto diff = [&](int h) -> float {
        float4 l = L4[(size_t)h * W + w];
        if (val) {
            float4 r = R4[(size_t)h * W + wr];
            return fabsf(l.x - r.x) + fabsf(l.y - r.y) + fabsf(l.z - r.z);
        }
        return fabsf(l.x) + fabsf(l.y) + fabsf(l.z);  // r_shift == 0 when invalid
    };

    // Warm-up: rows [h0-10, h0+9] -> ring slots 0..19, accumulate vs.
    float vs = 0.f;
    for (int k = 0; k < 20; ++k) {
        int h = h0 - R + k;                       // max h0+9 = 249 < H, only h>=0 guard
        float dv = (h >= 0) ? diff(h) : 0.f;
        ring[k][w] = dv;
        vs += dv;
    }
    ring[20][w] = 0.f;  // slot for row h0-11 (outside window) must subtract 0

    float* cp = cost + ((size_t)(b * D + d) * H) * W;
    const int cc = threadIdx.x >> 3;   // phase-2 col-run (0..63)
    const int jj = threadIdx.x & 7;    // phase-2 row slot (0..7)

    for (int ss = 0; ss < SEG / 8; ++ss) {
#pragma unroll
        for (int j = 0; j < 8; ++j) {
            int i = ss * 8 + j;                    // output row index in segment
            int slot = (i + 20) % 21;              // == (i-1) mod 21: read-then-overwrite
            int hn = h0 + i + R;                   // new diff row h+10
            float dv = (hn < H) ? diff(hn) : 0.f;
            float dold = ring[slot][w];
            ring[slot][w] = dv;
            vs += dv - dold;
            vsbuf[j][10 + w] = vs;
        }
        __syncthreads();
        {   // horizontal rolling: 28-float window -> 8 outputs
            const float* vp = &vsbuf[jj][8 * cc];
            float wnd[28];
#pragma unroll
            for (int q = 0; q < 7; ++q) {
                float4 v4 = *(const float4*)(vp + 4 * q);
                wnd[4 * q] = v4.x; wnd[4 * q + 1] = v4.y;
                wnd[4 * q + 2] = v4.z; wnd[4 * q + 3] = v4.w;
            }
            float o = 0.f;
#pragma unroll
            for (int k = 0; k < 21; ++k) o += wnd[k];
            float out[8];
            out[0] = o;
#pragma unroll
            for (int k = 1; k < 8; ++k) { o += wnd[20 + k] - wnd[k - 1]; out[k] = o; }
            float* op = cp + (size_t)(h0 + ss * 8 + jj) * W + 8 * cc;
            *(float4*)(op)     = make_float4(out[0], out[1], out[2], out[3]);
            *(float4*)(op + 4) = make_float4(out[4], out[5], out[6], out[7]);
        }
        __syncthreads();
    }
}

// argmin over d, 4 pixels per thread via float4; strict < keeps lowest d (jnp.argmin).
__global__ void k_argmin(const float* __restrict__ cost, float* __restrict__ disp) {
    int idx = blockIdx.x * 256 + threadIdx.x;      // over B*HW/4
    if (idx >= B * (HW / 4)) return;
    int b = idx / (HW / 4);
    int g = idx - b * (HW / 4);
    const float4* cp = (const float4*)cost + (size_t)b * D * (HW / 4) + g;
    float4 v0 = cp[0];
    float bb[4] = {v0.x, v0.y, v0.z, v0.w};
    int bd[4] = {0, 0, 0, 0};
#pragma unroll 4
    for (int d = 1; d < D; ++d) {
        float4 v = cp[(size_t)d * (HW / 4)];
        if (v.x < bb[0]) { bb[0] = v.x; bd[0] = d; }
        if (v.y < bb[1]) { bb[1] = v.y; bd[1] = d; }
        if (v.z < bb[2]) { bb[2] = v.z; bd[2] = d; }
        if (v.w < bb[3]) { bb[3] = v.w; bd[3] = d; }
    }
    ((float4*)disp)[idx] = make_float4((float)bd[0], (float)bd[1], (float)bd[2], (float)bd[3]);
}

// Deterministic two-stage mean-abs-diff reduction.
__global__ void k_red1(const float* __restrict__ a, const float* __restrict__ b2,
                       float* __restrict__ part, int n) {
    __shared__ float sm[256];
    int tid = threadIdx.x;
    float s = 0.f;
    for (int i = blockIdx.x * 256 + tid; i < n; i += gridDim.x * 256)
        s += fabsf(a[i] - b2[i]);
    sm[tid] = s;
    __syncthreads();
    for (int off = 128; off; off >>= 1) {
        if (tid < off) sm[tid] += sm[tid + off];
        __syncthreads();
    }
    if (!tid) part[blockIdx.x] = sm[0];
}

__global__ void k_red2(const float* __restrict__ part, float* __restrict__ out,
                       int nb, float inv) {
    __shared__ float sm[256];
    int tid = threadIdx.x;
    float s = 0.f;
    for (int i = tid; i < nb; i += 256) s += part[i];
    sm[tid] = s;
    __syncthreads();
    for (int off = 128; off; off >>= 1) {
        if (tid < off) sm[tid] += sm[tid + off];
        __syncthreads();
    }
    if (!tid) out[0] = sm[0] * inv;
}

extern "C" void kernel_launch(void* const* d_in, const int* in_sizes, int n_in,
                              void* d_out, int out_size, void* d_ws, size_t ws_size,
                              hipStream_t stream) {
    const float* x  = (const float*)d_in[0];
    const float* gt = (const float*)d_in[1];

    float4* nrm4 = (float4*)d_ws;                           // 21.0 MB
    float* cost  = (float*)(nrm4 + (size_t)2 * B * 2 * HW); // 83.9 MB
    float* disp  = cost + (size_t)B * D * HW;               // 2.6 MB
    float* part  = disp + (size_t)2 * B * HW;               // 640 floats

    k_norm<<<(2 * B * HW + 255) / 256, 256, 0, stream>>>(x, gt, nrm4);

    for (int t = 0; t < 2; ++t) {
        k_cost<<<B * NSEG * D, 512, 0, stream>>>(nrm4, cost, t);
        k_argmin<<<(B * (HW / 4) + 255) / 256, 256, 0, stream>>>(cost, disp + (size_t)t * B * HW);
    }

    constexpr int NB = 640;
    k_red1<<<NB, 256, 0, stream>>>(disp, disp + (size_t)B * HW, part, B * HW);
    k_red2<<<1, 256, 0, stream>>>(part, (float*)d_out, NB, 1.f / (float)(B * HW));
}